// Round 4
// baseline (667.198 us; speedup 1.0000x reference)
//
#include <hip/hip_runtime.h>
#include <cstddef>

#define B_       512
#define IN_      1023
#define INP1     1024
#define OUT_     512
#define OUT4     128      // OUT_/4
#define CLIPV    2.0f
#define LNEPS    1e-5f
#define SLABS    4        // i-slabs per sample
#define SLABROWS 256      // INP1/SLABS
#define NBS      (B_ * SLABS)   // 2048 (b,s) tiles

typedef float fx4 __attribute__((ext_vector_type(4)));

// block-wide sum-reduction of two floats. blockDim.x multiple of 64, <=1024.
__device__ __forceinline__ float2 block_reduce2(float a, float b, float2* lds) {
    #pragma unroll
    for (int off = 32; off; off >>= 1) {
        a += __shfl_down(a, off, 64);
        b += __shfl_down(b, off, 64);
    }
    const int lane = threadIdx.x & 63;
    const int wid  = threadIdx.x >> 6;
    const int nw   = blockDim.x >> 6;
    if (lane == 0) lds[wid] = make_float2(a, b);
    __syncthreads();
    if (wid == 0) {
        float2 v = (lane < nw) ? lds[lane] : make_float2(0.f, 0.f);
        a = v.x; b = v.y;
        #pragma unroll
        for (int off = 8; off; off >>= 1) {
            a += __shfl_down(a, off, 64);
            b += __shfl_down(b, off, 64);
        }
        if (lane == 0) lds[0] = make_float2(a, b);
    }
    __syncthreads();
    float2 r = lds[0];
    __syncthreads();
    return r;
}

// XCD-aware decode: all blocks on one XCD share the same i-slab s, so each
// XCD's L2 only needs 1 MiB of weight+alpha (vs 4 MiB unswizzled).
__device__ __forceinline__ void decode_bs(int raw, int& b, int& s) {
    const int xcd = raw & 7;          // blockIdx % 8 ~ physical XCD
    const int idx = raw >> 3;         // 0..255
    s = xcd & 3;
    b = idx + ((xcd >> 2) << 8);      // 0..511
}

// k1a: partial y_pre per (sample b, i-slab s). 2048 blocks x 256 threads.
// hebb streamed with nontemporal loads (don't evict W/alpha from L2).
__global__ __launch_bounds__(256) void k1a_partial(
    const float* __restrict__ x, const float* __restrict__ hebb,
    const float* __restrict__ weight, const float* __restrict__ alpha,
    float* __restrict__ ws_part)
{
    int b, s;
    decode_bs((int)blockIdx.x, b, s);
    const int bs   = b * SLABS + s;
    const int tid  = threadIdx.x;
    const int o4   = tid & 127;
    const int half = tid >> 7;          // 0..1

    __shared__ float  xs[SLABROWS];
    __shared__ float4 part[2][OUT4];

    {
        const int i = s * SLABROWS + tid;
        xs[tid] = (i < IN_) ? x[(size_t)b * IN_ + i] : 1.0f;  // bias row = 1
    }
    __syncthreads();

    const int i0 = s * SLABROWS + half * 128;
    const fx4*    __restrict__ h4 = (const fx4*)hebb    + ((size_t)b * INP1 + i0) * OUT4 + o4;
    const float4* __restrict__ w4 = (const float4*)weight + (size_t)i0 * OUT4 + o4;
    const float4* __restrict__ a4 = (const float4*)alpha  + (size_t)i0 * OUT4 + o4;
    const float*  __restrict__ xk = xs + half * 128;

    float4 acc = make_float4(0.f, 0.f, 0.f, 0.f);
    #pragma unroll 4
    for (int k = 0; k < 128; ++k) {
        const float  xv = xk[k];
        const fx4    h  = __builtin_nontemporal_load(&h4[(size_t)k * OUT4]);
        const float4 w  = w4[(size_t)k * OUT4];
        const float4 a  = a4[(size_t)k * OUT4];
        acc.x = fmaf(xv, fmaf(a.x, h.x, w.x), acc.x);
        acc.y = fmaf(xv, fmaf(a.y, h.y, w.y), acc.y);
        acc.z = fmaf(xv, fmaf(a.z, h.z, w.z), acc.z);
        acc.w = fmaf(xv, fmaf(a.w, h.w, w.w), acc.w);
    }

    part[half][o4] = acc;
    __syncthreads();
    if (half == 0) {
        float4 p = part[0][o4];
        const float4 q = part[1][o4];
        p.x += q.x; p.y += q.y; p.z += q.z; p.w += q.w;
        ((float4*)ws_part)[(size_t)bs * OUT4 + o4] = p;
    }
}

// k1b: reduce SLABS partials -> LayerNorm -> tanh -> y, m. 512 blocks x 512 thr.
__global__ __launch_bounds__(512) void k1b_ln_mod(
    const float* __restrict__ ws_part,
    const float* __restrict__ ln_g, const float* __restrict__ ln_b,
    const float* __restrict__ mod_w, const float* __restrict__ mod_b,
    float* __restrict__ y_out, float* __restrict__ m_out)
{
    const int b = blockIdx.x;
    const int o = threadIdx.x;
    __shared__ float2 rbuf[16];

    float ypre = 0.f;
    #pragma unroll
    for (int s = 0; s < SLABS; ++s)
        ypre += ws_part[((size_t)b * SLABS + s) * OUT_ + o];

    float2 ss = block_reduce2(ypre, ypre * ypre, rbuf);
    const float mu   = ss.x * (1.0f / OUT_);
    const float var  = ss.y * (1.0f / OUT_) - mu * mu;
    const float rstd = rsqrtf(var + LNEPS);

    const float yv = tanhf(fmaf(ln_g[o], (ypre - mu) * rstd, ln_b[o]));
    y_out[(size_t)b * OUT_ + o] = yv;

    float2 ms = block_reduce2(yv * mod_w[o], 0.f, rbuf);
    if (o == 0) m_out[b] = tanhf(ms.x + mod_b[0]);
}

// k2: hebb_new = clip(hebb + coef_o * x_i, +-CLIP), coef_o = (m*fw_o+fb_o)*y_o.
// Reverse-swizzled so its first blocks re-read what k1a read LAST (L3-hot).
// Inner loop: 1 NT float4 load + 1 NT float4 store.
__global__ __launch_bounds__(256) void k2_update(
    const float* __restrict__ x, const float* __restrict__ hebb,
    const float* __restrict__ y, const float* __restrict__ m,
    const float* __restrict__ fan_w, const float* __restrict__ fan_b,
    float* __restrict__ hebb_out)
{
    int b, s;
    decode_bs(NBS - 1 - (int)blockIdx.x, b, s);
    const int tid  = threadIdx.x;
    const int o4   = tid & 127;
    const int half = tid >> 7;

    __shared__ float xs[SLABROWS];
    {
        const int i = s * SLABROWS + tid;
        xs[tid] = (i < IN_) ? x[(size_t)b * IN_ + i] : 1.0f;
    }
    __syncthreads();

    const float  mb = m[b];
    const float4 yv = ((const float4*)y)[(size_t)b * OUT4 + o4];
    const float4 fw = ((const float4*)fan_w)[o4];
    const float4 fb = ((const float4*)fan_b)[o4];
    float4 coef;
    coef.x = fmaf(mb, fw.x, fb.x) * yv.x;
    coef.y = fmaf(mb, fw.y, fb.y) * yv.y;
    coef.z = fmaf(mb, fw.z, fb.z) * yv.z;
    coef.w = fmaf(mb, fw.w, fb.w) * yv.w;

    const int i0 = s * SLABROWS + half * 128;
    const size_t base = ((size_t)b * INP1 + i0) * OUT4 + o4;
    const fx4* __restrict__ h4  = (const fx4*)hebb + base;
    fx4* __restrict__       ho4 = (fx4*)hebb_out + base;
    const float* __restrict__ xk = xs + half * 128;

    #pragma unroll 4
    for (int k = 0; k < 128; ++k) {
        const float xv = xk[k];
        const fx4   h  = __builtin_nontemporal_load(&h4[(size_t)k * OUT4]);
        fx4 r;
        r.x = fminf(fmaxf(fmaf(coef.x, xv, h.x), -CLIPV), CLIPV);
        r.y = fminf(fmaxf(fmaf(coef.y, xv, h.y), -CLIPV), CLIPV);
        r.z = fminf(fmaxf(fmaf(coef.z, xv, h.z), -CLIPV), CLIPV);
        r.w = fminf(fmaxf(fmaf(coef.w, xv, h.w), -CLIPV), CLIPV);
        __builtin_nontemporal_store(r, &ho4[(size_t)k * OUT4]);
    }
}

extern "C" void kernel_launch(void* const* d_in, const int* in_sizes, int n_in,
                              void* d_out, int out_size, void* d_ws, size_t ws_size,
                              hipStream_t stream) {
    const float* x      = (const float*)d_in[0];
    const float* hebb   = (const float*)d_in[1];
    const float* weight = (const float*)d_in[2];
    const float* alpha  = (const float*)d_in[3];
    const float* ln_g   = (const float*)d_in[4];
    const float* ln_b   = (const float*)d_in[5];
    const float* mod_w  = (const float*)d_in[6];
    const float* mod_b  = (const float*)d_in[7];
    const float* fan_w  = (const float*)d_in[8];
    const float* fan_b  = (const float*)d_in[9];

    float* out      = (float*)d_out;
    float* y_out    = out;                               // [B, OUT]
    float* m_out    = out + (size_t)B_ * OUT_;           // [B]
    float* hebb_out = m_out + B_;                        // [B, IN+1, OUT]

    // partial-sum scratch: B*SLABS*OUT floats = 4 MiB
    const size_t part_bytes = (size_t)B_ * SLABS * OUT_ * sizeof(float);
    float* ws_part = (ws_size >= part_bytes) ? (float*)d_ws
                                             : hebb_out;  // consumed by k1b first

    k1a_partial<<<NBS, 256, 0, stream>>>(x, hebb, weight, alpha, ws_part);
    k1b_ln_mod<<<B_, OUT_, 0, stream>>>(ws_part, ln_g, ln_b, mod_w, mod_b,
                                        y_out, m_out);
    k2_update<<<NBS, 256, 0, stream>>>(x, hebb, y_out, m_out,
                                       fan_w, fan_b, hebb_out);
}